// Round 1
// baseline (196.120 us; speedup 1.0000x reference)
//
#include <hip/hip_runtime.h>

typedef __attribute__((ext_vector_type(4))) float f32x4;
typedef __attribute__((ext_vector_type(4))) short s16x4;
typedef __attribute__((ext_vector_type(4))) unsigned int u32x4;

// float -> bf16 bits, round-nearest-even
__device__ __forceinline__ unsigned int f2bf(float f) {
  unsigned int u = __float_as_uint(f);
  u += 0x7fffu + ((u >> 16) & 1u);
  return u >> 16;
}

// ---------------------------------------------------------------------------
// Kernel 0: repack weight [Cout=128][Cin=128][3][3] fp32 into bf16 in MFMA
// A-fragment order:
//   wfrag[ch=tap*4+cc][MT=co/16][kh][lane][j]  (ushort)
//   element = weight[ MT*16 + (lane&15) ][ cc*32 + kh*16 + 4*(lane>>4) + j ][ tap ]
// so the GEMM A-load is a coalesced 8B/lane read. 36*8*2*64*4 = 147456 ushorts
// = 294912 bytes of d_ws. Rewritten fully every launch (ws is re-poisoned).
// ---------------------------------------------------------------------------
__global__ __launch_bounds__(256) void wtrans_kernel(const float* __restrict__ w,
                                                     unsigned short* __restrict__ wf) {
  int tid = blockIdx.x * 256 + threadIdx.x;  // 0..36863
  int l  = tid & 63;
  int kh = (tid >> 6) & 1;
  int mt = (tid >> 7) & 7;
  int ch = tid >> 10;          // 0..35
  int cc = ch & 3, tap = ch >> 2;
  int co = mt * 16 + (l & 15);
  int cb = cc * 32 + kh * 16 + 4 * (l >> 4);
  unsigned int r0 = f2bf(w[(co * 128 + cb + 0) * 9 + tap]);
  unsigned int r1 = f2bf(w[(co * 128 + cb + 1) * 9 + tap]);
  unsigned int r2 = f2bf(w[(co * 128 + cb + 2) * 9 + tap]);
  unsigned int r3 = f2bf(w[(co * 128 + cb + 3) * 9 + tap]);
  uint2 pk;
  pk.x = r0 | (r1 << 16);
  pk.y = r2 | (r3 << 16);
  *reinterpret_cast<uint2*>(wf + tid * 4) = pk;
}

// ---------------------------------------------------------------------------
// Main fused kernel: one block = (batch b, output row ho), 256 threads.
// Waves split Cout into 4x32; K = Cin*9 = 1152 looped in 36 chunks of 32.
// Per chunk: threads gather+bilinear-interp a [32c x 64n] bf16 cols tile into
// LDS, then each wave does 16 v_mfma_f32_16x16x16bf16_1k (2 m-tiles x 4
// n-tiles x 2 k-halves). A-fragments stream from pre-repacked global (L2).
// b = bid&7 pins each batch's 2MB x-plane to one XCD's L2.
// ---------------------------------------------------------------------------
__global__ __launch_bounds__(256, 2) void deform_kernel(const float* __restrict__ x,
                                                        const float* __restrict__ off,
                                                        const unsigned short* __restrict__ wf,
                                                        float* __restrict__ out) {
  __shared__ int4   sPos[576];              // [k*64+n] 4 clamped spatial offsets
  __shared__ float4 sWt[576];               // [k*64+n] validity-folded bilinear wts
  __shared__ unsigned short sCols[64 * 40]; // cols tile [n][c_local], stride 40 (pad)

  const int tid = threadIdx.x;
  const int bid = blockIdx.x;
  const int b  = bid & 7;                   // XCD-affine batch
  const int ho = bid >> 3;

  // --- per-block precompute: sampling positions/weights for all 9 taps ---
  for (int r = tid; r < 576; r += 256) {
    int k = r >> 6, n = r & 63;
    float dy = off[((b * 18 + 2 * k)     * 64 + ho) * 64 + n];
    float dx = off[((b * 18 + 2 * k + 1) * 64 + ho) * 64 + n];
    float py = (float)(ho + (k / 3) - 1) + dy;
    float px = (float)(n  + (k % 3) - 1) + dx;
    float fy = floorf(py), fx = floorf(px);
    int y0 = (int)fy, x0 = (int)fx;
    float wy = py - fy, wx = px - fx;
    int y1 = y0 + 1, x1 = x0 + 1;
    float v00 = (y0 >= 0 && y0 < 64 && x0 >= 0 && x0 < 64) ? 1.f : 0.f;
    float v01 = (y0 >= 0 && y0 < 64 && x1 >= 0 && x1 < 64) ? 1.f : 0.f;
    float v10 = (y1 >= 0 && y1 < 64 && x0 >= 0 && x0 < 64) ? 1.f : 0.f;
    float v11 = (y1 >= 0 && y1 < 64 && x1 >= 0 && x1 < 64) ? 1.f : 0.f;
    int y0c = min(max(y0, 0), 63), y1c = min(max(y1, 0), 63);
    int x0c = min(max(x0, 0), 63), x1c = min(max(x1, 0), 63);
    sPos[r] = make_int4(y0c * 64 + x0c, y0c * 64 + x1c,
                        y1c * 64 + x0c, y1c * 64 + x1c);
    sWt[r] = make_float4((1.f - wy) * (1.f - wx) * v00,
                         (1.f - wy) * wx         * v01,
                         wy         * (1.f - wx) * v10,
                         wy         * wx         * v11);
  }
  __syncthreads();

  f32x4 acc[2][4] = {};
  const int n  = tid & 63;   // spatial position handled in gather phase
  const int cb = tid >> 6;   // c-subchunk in gather phase; wave id in MFMA phase
  const int q  = n >> 4, ln = n & 15;

  for (int cc = 0; cc < 4; ++cc) {        // c-chunk outer: x-plane reuse across taps
    for (int k = 0; k < 9; ++k) {
      const int ch = k * 4 + cc;

      // ---- phase 1: gather + bilinear interp, 8 channels per thread ----
      const int4   o  = sPos[k * 64 + n];
      const float4 wv = sWt[k * 64 + n];
      const float* xp = x + (size_t)(b * 128 + cc * 32 + cb * 8) * 4096;
      float av[8];
#pragma unroll
      for (int jj = 0; jj < 8; ++jj) {
        av[jj] = wv.x * xp[o.x] + wv.y * xp[o.y] + wv.z * xp[o.z] + wv.w * xp[o.w];
        xp += 4096;
      }
      __syncthreads();  // previous chunk's B-frag reads complete
      u32x4 pk;
      pk.x = f2bf(av[0]) | (f2bf(av[1]) << 16);
      pk.y = f2bf(av[2]) | (f2bf(av[3]) << 16);
      pk.z = f2bf(av[4]) | (f2bf(av[5]) << 16);
      pk.w = f2bf(av[6]) | (f2bf(av[7]) << 16);
      *reinterpret_cast<u32x4*>(&sCols[n * 40 + cb * 8]) = pk;
      __syncthreads();  // cols tile visible

      // ---- phase 2: MFMA. wave cb -> Cout rows [32*cb, 32*cb+32) ----
      const unsigned short* wfp = wf + (ch * 8 + cb * 2) * 512;
#pragma unroll
      for (int kh = 0; kh < 2; ++kh) {
        s16x4 a0 = *reinterpret_cast<const s16x4*>(wfp +       kh * 256 + n * 4);
        s16x4 a1 = *reinterpret_cast<const s16x4*>(wfp + 512 + kh * 256 + n * 4);
#pragma unroll
        for (int nt = 0; nt < 4; ++nt) {
          s16x4 bf = *reinterpret_cast<const s16x4*>(
              &sCols[(nt * 16 + ln) * 40 + kh * 16 + 4 * q]);
          acc[0][nt] = __builtin_amdgcn_mfma_f32_16x16x16bf16_1k(a0, bf, acc[0][nt], 0, 0, 0);
          acc[1][nt] = __builtin_amdgcn_mfma_f32_16x16x16bf16_1k(a1, bf, acc[1][nt], 0, 0, 0);
        }
      }
    }
  }

  // ---- epilogue: C/D layout col=lane&15, row=4*(lane>>4)+reg ----
#pragma unroll
  for (int mt = 0; mt < 2; ++mt)
#pragma unroll
    for (int nt = 0; nt < 4; ++nt)
#pragma unroll
      for (int rg = 0; rg < 4; ++rg) {
        int co = cb * 32 + mt * 16 + q * 4 + rg;
        out[((b * 128 + co) * 64 + ho) * 64 + nt * 16 + ln] = acc[mt][nt][rg];
      }
}

extern "C" void kernel_launch(void* const* d_in, const int* in_sizes, int n_in,
                              void* d_out, int out_size, void* d_ws, size_t ws_size,
                              hipStream_t stream) {
  (void)in_sizes; (void)n_in; (void)out_size; (void)ws_size;
  const float* x   = (const float*)d_in[0];
  const float* off = (const float*)d_in[1];
  const float* w   = (const float*)d_in[2];
  float* out = (float*)d_out;
  unsigned short* wf = (unsigned short*)d_ws;  // 294912 bytes

  wtrans_kernel<<<144, 256, 0, stream>>>(w, wf);
  deform_kernel<<<512, 256, 0, stream>>>(x, off, wf, out);
}

// Round 2
// 157.486 us; speedup vs baseline: 1.2453x; 1.2453x over previous
//
#include <hip/hip_runtime.h>

typedef __attribute__((ext_vector_type(4))) float f32x4;
typedef __attribute__((ext_vector_type(8))) short s16x8;
typedef __attribute__((ext_vector_type(4))) unsigned int u32x4;

// float -> bf16 bits, round-nearest-even
__device__ __forceinline__ unsigned int f2bf(float f) {
  unsigned int u = __float_as_uint(f);
  u += 0x7fffu + ((u >> 16) & 1u);
  return u >> 16;
}

// ---------------------------------------------------------------------------
// Kernel 0: repack weight [128][128][3][3] fp32 -> bf16 MFMA A-fragments for
// v_mfma_f32_16x16x32_bf16:
//   wf[((ch*8 + mt)*64 + lane)*8 + j] = bf16(W[mt*16+(lane&15)]
//                                            [cc*32 + (lane>>4)*8 + j][tap])
// with ch = cc*9 + tap (cc = Cin/32 chunk, tap = kernel tap). A-load in the
// main kernel is then a coalesced 16B/lane read. 294912 B of d_ws.
// ---------------------------------------------------------------------------
__global__ __launch_bounds__(256) void wtrans_kernel(const float* __restrict__ w,
                                                     unsigned short* __restrict__ wf) {
  int tid = blockIdx.x * 256 + threadIdx.x;   // 0..18431
  int l  = tid & 63;
  int mt = (tid >> 6) & 7;
  int ch = tid >> 9;                          // 0..35
  int cc = ch / 9, tap = ch - cc * 9;
  int co = mt * 16 + (l & 15);
  int cb = cc * 32 + (l >> 4) * 8;
  unsigned int r[8];
#pragma unroll
  for (int j = 0; j < 8; ++j)
    r[j] = f2bf(w[(co * 128 + cb + j) * 9 + tap]);
  u32x4 pk;
  pk.x = r[0] | (r[1] << 16);
  pk.y = r[2] | (r[3] << 16);
  pk.z = r[4] | (r[5] << 16);
  pk.w = r[6] | (r[7] << 16);
  *reinterpret_cast<u32x4*>(wf + (size_t)tid * 8) = pk;
}

// ---------------------------------------------------------------------------
// Main fused kernel: block = (b, ho, half-row of 32 wo), 1024 blocks x 256.
// 4 blocks/CU -> 16 waves/CU. K = 1152 in 36 chunks of 32, software-pipelined:
// chunk ch+1's gather loads + A-frags issue before chunk ch's interpolation,
// so global latency overlaps interp + barrier + MFMA. sCols double-buffered
// (one barrier per chunk). Separable bilinear: per sample 2 row-pair loads
// (addr, addr+4B) with validity folded into 4 weights.
// b = bid&7 keeps each batch's 2 MB x-plane XCD-affine for L2 residency.
// ---------------------------------------------------------------------------
__global__ __launch_bounds__(256, 4) void deform_kernel(const float* __restrict__ x,
                                                        const float* __restrict__ off,
                                                        const unsigned short* __restrict__ wf,
                                                        float* __restrict__ out) {
  __shared__ int2   sPos[288];                  // [tap*32+n] row0/row1 base addrs
  __shared__ float4 sWt[288];                   // [tap*32+n] folded bilinear wts
  __shared__ unsigned short sCols[2][32 * 40];  // [buf][n][k] stride 40 (pad)

  const int tid = threadIdx.x;
  const int bid = blockIdx.x;
  const int b  = bid & 7;                       // XCD-affine batch
  const int wh = (bid >> 3) & 1;
  const int ho = bid >> 4;

  // --- precompute sampling addresses + separable folded weights ---
  for (int r = tid; r < 288; r += 256) {
    int tap = r >> 5, n = r & 31;
    int wo = wh * 32 + n;
    float dy = off[((b * 18 + 2 * tap)     * 64 + ho) * 64 + wo];
    float dx = off[((b * 18 + 2 * tap + 1) * 64 + ho) * 64 + wo];
    float py = (float)(ho + (tap / 3) - 1) + dy;
    float px = (float)(wo + (tap % 3) - 1) + dx;
    float fy = floorf(py), fx = floorf(px);
    int y0 = (int)fy, x0 = (int)fx;
    float wy = py - fy, wx = px - fx;
    // rows: weight * validity, clamped addresses
    float wt = (y0 >= 0 && y0 < 64) ? (1.f - wy) : 0.f;
    float wb = (y0 + 1 >= 0 && y0 + 1 < 64) ? wy : 0.f;
    int y0c = min(max(y0, 0), 63), y1c = min(max(y0 + 1, 0), 63);
    // cols: shifted-base trick so (X[bx], X[bx+1]) covers valid taps
    int bx; float wl, wr;
    if (x0 >= 0 && x0 <= 62)      { bx = x0; wl = 1.f - wx; wr = wx;       }
    else if (x0 == -1)            { bx = 0;  wl = wx;       wr = 0.f;      }
    else if (x0 == 63)            { bx = 62; wl = 0.f;      wr = 1.f - wx; }
    else                          { bx = 0;  wl = 0.f;      wr = 0.f;      }
    sPos[r] = make_int2(y0c * 64 + bx, y1c * 64 + bx);
    sWt[r]  = make_float4(wt * wl, wt * wr, wb * wl, wb * wr);
  }
  __syncthreads();

  const int n  = tid & 31;        // gather: spatial position
  const int c4 = tid >> 5;        // gather: 4-channel group 0..7
  const int wv = tid >> 6;        // mfma: wave -> Cout rows [32wv,32wv+32)
  const int ln = tid & 15, q = (tid >> 4) & 3;
  const float* xb = x + (size_t)(b * 128 + c4 * 4) * 4096;
  const unsigned short* wfb = wf + ((size_t)(wv * 2) * 64 + (tid & 63)) * 8;

  f32x4 acc[2][2] = {};
  float2 RA[8], RB[8];
  s16x8 AA[2], AB[2];

#define ISSUE(CH, R, A)                                                        \
  {                                                                            \
    int cc_ = (CH) / 9, tap_ = (CH) - cc_ * 9;                                 \
    int2 a_ = sPos[tap_ * 32 + n];                                             \
    const float* p_ = xb + (size_t)cc_ * 32 * 4096;                            \
    _Pragma("unroll")                                                          \
    for (int i_ = 0; i_ < 4; ++i_) {                                           \
      __builtin_memcpy(&R[2 * i_],     p_ + a_.x, 8);                          \
      __builtin_memcpy(&R[2 * i_ + 1], p_ + a_.y, 8);                          \
      p_ += 4096;                                                              \
    }                                                                          \
    const s16x8* wp_ = reinterpret_cast<const s16x8*>(wfb + (size_t)(CH) * 8 * 64 * 8); \
    A[0] = wp_[0];                                                             \
    A[1] = wp_[64];                                                            \
  }

#define INTERP_WRITE(CH, R, BUF)                                               \
  {                                                                            \
    int cc_ = (CH) / 9, tap_ = (CH) - cc_ * 9;                                 \
    float4 w_ = sWt[tap_ * 32 + n];                                            \
    float v0_ = w_.x * R[0].x + w_.y * R[0].y + w_.z * R[1].x + w_.w * R[1].y; \
    float v1_ = w_.x * R[2].x + w_.y * R[2].y + w_.z * R[3].x + w_.w * R[3].y; \
    float v2_ = w_.x * R[4].x + w_.y * R[4].y + w_.z * R[5].x + w_.w * R[5].y; \
    float v3_ = w_.x * R[6].x + w_.y * R[6].y + w_.z * R[7].x + w_.w * R[7].y; \
    uint2 pk_;                                                                 \
    pk_.x = f2bf(v0_) | (f2bf(v1_) << 16);                                     \
    pk_.y = f2bf(v2_) | (f2bf(v3_) << 16);                                     \
    *reinterpret_cast<uint2*>(&sCols[BUF][n * 40 + c4 * 4]) = pk_;             \
  }

#define DOMFMA(A, BUF)                                                         \
  {                                                                            \
    _Pragma("unroll")                                                          \
    for (int nt_ = 0; nt_ < 2; ++nt_) {                                        \
      s16x8 bf_ = *reinterpret_cast<const s16x8*>(                             \
          &sCols[BUF][(nt_ * 16 + ln) * 40 + q * 8]);                          \
      acc[0][nt_] = __builtin_amdgcn_mfma_f32_16x16x32_bf16(A[0], bf_, acc[0][nt_], 0, 0, 0); \
      acc[1][nt_] = __builtin_amdgcn_mfma_f32_16x16x32_bf16(A[1], bf_, acc[1][nt_], 0, 0, 0); \
    }                                                                          \
  }

  ISSUE(0, RA, AA)
  for (int chp = 0; chp < 18; ++chp) {
    int ch0 = chp * 2;
    ISSUE(ch0 + 1, RB, AB)
    INTERP_WRITE(ch0, RA, 0)
    __syncthreads();
    DOMFMA(AA, 0)
    if (chp < 17) ISSUE(ch0 + 2, RA, AA)
    INTERP_WRITE(ch0 + 1, RB, 1)
    __syncthreads();
    DOMFMA(AB, 1)
  }

  // epilogue: C/D layout col = lane&15, row = (lane>>4)*4 + reg
#pragma unroll
  for (int mt = 0; mt < 2; ++mt)
#pragma unroll
    for (int nt = 0; nt < 2; ++nt)
#pragma unroll
      for (int rg = 0; rg < 4; ++rg) {
        int co = wv * 32 + mt * 16 + q * 4 + rg;
        out[((b * 128 + co) * 64 + ho) * 64 + wh * 32 + nt * 16 + ln] = acc[mt][nt][rg];
      }
}

extern "C" void kernel_launch(void* const* d_in, const int* in_sizes, int n_in,
                              void* d_out, int out_size, void* d_ws, size_t ws_size,
                              hipStream_t stream) {
  (void)in_sizes; (void)n_in; (void)out_size; (void)ws_size;
  const float* x   = (const float*)d_in[0];
  const float* off = (const float*)d_in[1];
  const float* w   = (const float*)d_in[2];
  float* out = (float*)d_out;
  unsigned short* wf = (unsigned short*)d_ws;  // 294912 bytes

  wtrans_kernel<<<72, 256, 0, stream>>>(w, wf);
  deform_kernel<<<1024, 256, 0, stream>>>(x, off, wf, out);
}